// Round 6
// baseline (776.929 us; speedup 1.0000x reference)
//
#include <hip/hip_runtime.h>
#include <math.h>

#define BB 16
#define CC 256
#define HH 64
#define WW 64
#define HWs 4096
#define PP 65536   // BB*HWs
#define QQ 8
#define NN 9

typedef _Float16 half8_t __attribute__((ext_vector_type(8)));
typedef _Float16 half4_t __attribute__((ext_vector_type(4)));
typedef _Float16 half2_t __attribute__((ext_vector_type(2)));
typedef float floatx4 __attribute__((ext_vector_type(4)));

__device__ __forceinline__ float gelu_f(float x) {
    return 0.5f * x * (1.0f + erff(x * 0.70710678118654752f));
}

// ---------------- weight prep ----------------
__global__ void prep_weights_kernel(const float* __restrict__ off0_w, const float* __restrict__ off1_w,
                                    const float* __restrict__ dw0_w, const float* __restrict__ dw1_w,
                                    const float* __restrict__ op1_w,
                                    const float* __restrict__ in_w, const float* __restrict__ cv_w,
                                    const float* __restrict__ op0_w, const float* __restrict__ op2_w,
                                    const float* __restrict__ out0_w, const float* __restrict__ out1_w,
                                    float* __restrict__ dwt0, float* __restrict__ dwt1,
                                    float* __restrict__ op1t,
                                    _Float16* __restrict__ wh_in, _Float16* __restrict__ wh_cv,
                                    _Float16* __restrict__ wh_op0, _Float16* __restrict__ wh_op2,
                                    _Float16* __restrict__ wh_out0, _Float16* __restrict__ wh_out1,
                                    _Float16* __restrict__ whoff0, _Float16* __restrict__ whoff1) {
    int i = blockIdx.x * 256 + threadIdx.x;
    if (i < 9*256) {
        int c = i & 255;
        int tap = i >> 8;
        dwt0[i] = dw0_w[c*9 + tap];
        dwt1[i] = dw1_w[c*9 + tap];
        op1t[i] = op1_w[c*9 + tap];
    }
    if (i < 65536) {            // [256][256] f16 direct casts
        wh_in[i]  = (_Float16)in_w[i];
        wh_cv[i]  = (_Float16)cv_w[i];
        wh_op0[i] = (_Float16)op0_w[i];
        wh_op2[i] = (_Float16)op2_w[i];
    }
    if (i < 32768) {            // out0: [128][256], out1: [256][128]
        wh_out0[i] = (_Float16)out0_w[i];
        wh_out1[i] = (_Float16)out1_w[i];
    }
    if (i < 9*32*256) {         // whoff[tap][k32][ci], zero-padded k>=27
        int ci = i & 255;
        int k32 = (i >> 8) & 31;
        int tap = i >> 13;
        float v0 = 0.f, v1 = 0.f;
        if (k32 < 27) {
            v0 = off0_w[(k32*256 + ci)*9 + tap];
            v1 = off1_w[(k32*256 + ci)*9 + tap];
        }
        whoff0[i] = (_Float16)v0;
        whoff1[i] = (_Float16)v1;
    }
}

// ---------------- token path ----------------
__global__ void token_kernel(const float* __restrict__ inter, const float* __restrict__ intra,
                             const float* __restrict__ proj_w, const float* __restrict__ proj_b,
                             const float* __restrict__ lin_w, const float* __restrict__ lin_b,
                             const float* __restrict__ tok_g, const float* __restrict__ tok_b,
                             float* __restrict__ t_out) {
    int bq = blockIdx.x;
    int b = bq >> 3, q = bq & 7;
    int c = threadIdx.x;
    __shared__ float inter_s[256];
    __shared__ float pt_s[9];
    __shared__ float g_s[256];
    __shared__ float red[256];
    __shared__ float stat[2];
    inter_s[c] = inter[(b*QQ + q)*CC + c];
    __syncthreads();
    for (int n = 0; n < 9; n++) {
        red[c] = inter_s[c] * intra[(b*NN + n)*CC + c];
        __syncthreads();
        for (int s = 128; s > 0; s >>= 1) {
            if (c < s) red[c] += red[c + s];
            __syncthreads();
        }
        if (c == 0) pt_s[n] = red[0];
        __syncthreads();
    }
    float u = proj_b[c];
    for (int k = 0; k < 256; k++) u += inter_s[k] * proj_w[k*CC + c];
    for (int n = 0; n < 9; n++) u += pt_s[n] * proj_w[(256 + n)*CC + c];
    g_s[c] = gelu_f(u);
    __syncthreads();
    float v = lin_b[c];
    for (int k = 0; k < 256; k++) v += g_s[k] * lin_w[k*CC + c];
    red[c] = v;
    __syncthreads();
    for (int s = 128; s > 0; s >>= 1) { if (c < s) red[c] += red[c + s]; __syncthreads(); }
    if (c == 0) stat[0] = red[0] * (1.0f/256.0f);
    __syncthreads();
    float m = stat[0];
    red[c] = (v - m)*(v - m);
    __syncthreads();
    for (int s = 128; s > 0; s >>= 1) { if (c < s) red[c] += red[c + s]; __syncthreads(); }
    if (c == 0) stat[1] = red[0] * (1.0f/256.0f);
    __syncthreads();
    float var = stat[1];
    float r = rsqrtf(var + 1e-5f);
    t_out[(b*QQ + q)*CC + c] = (v - m) * r * tok_g[c] + tok_b[c];
}

// ---------------- img = ie*(1+pe), NCHW -> NHWC transpose, f16 out ----------------
__global__ void img_pe_kernel(const float* __restrict__ ie, const float* __restrict__ intra,
                              const float* __restrict__ masks, _Float16* __restrict__ img) {
    int b = blockIdx.z;
    int c0 = blockIdx.y * 32;
    int s0 = blockIdx.x * 32;
    __shared__ float tile[32][33];
    __shared__ float intra_s[9][32];
    __shared__ float mask_s[9][32];
    int tx = threadIdx.x, ty = threadIdx.y;
    int t = ty*32 + tx;
    for (int i = t; i < 288; i += 256) {
        int n = i >> 5, j = i & 31;
        intra_s[n][j] = intra[(b*NN + n)*CC + c0 + j];
        mask_s[n][j]  = masks[(b*NN + n)*HWs + s0 + j];
    }
    __syncthreads();
    #pragma unroll
    for (int r = 0; r < 4; r++) {
        int cl = ty + 8*r;
        float val = ie[(b*CC + c0 + cl)*HWs + s0 + tx];
        float pe = 0.f;
        #pragma unroll
        for (int n = 0; n < 9; n++) pe += intra_s[n][cl] * mask_s[n][tx];
        tile[cl][tx] = val * (1.0f + pe);
    }
    __syncthreads();
    #pragma unroll
    for (int r = 0; r < 4; r++) {
        int sl = ty + 8*r;
        img[(b*HWs + s0 + sl)*CC + c0 + tx] = (_Float16)tile[tx][sl];
    }
}

// ---------------- MFMA 1x1 conv (GEMM), f16 in ----------------
// RES: 0 none, 2 f16 residual (perm layout)
// OUT: 1 = f16 out with permuted-B packed stores (thread holds NF consecutive co)
template<int CI, int CO, int ACT, int RES, int OUT>
__global__ void __launch_bounds__(256) conv1x1_mfma(const _Float16* __restrict__ in, const _Float16* __restrict__ Wh,
        const float* __restrict__ bias, const _Float16* __restrict__ res, float* __restrict__ out,
        _Float16* __restrict__ outh) {
    constexpr int KS = CI/32;        // k-steps
    constexpr int NF = CO/64;        // n-frags per wave
    constexpr int LDR = CI + 8;      // halves per LDS row (+16B pad)
    __shared__ __align__(16) _Float16 a_lds[64*LDR];
    int t = threadIdx.x;
    int wid = t >> 6, lane = t & 63;
    int quad = lane >> 4, l16 = lane & 15;
    int p0 = blockIdx.x * 64;
    {
        const half8_t* inh = (const half8_t*)in + (size_t)p0*(CI/8);
        for (int i = t; i < 64*(CI/8); i += 256) {
            int r = i/(CI/8), c8 = i%(CI/8);
            *(half8_t*)&a_lds[r*LDR + c8*8] = inh[i];
        }
    }
    __syncthreads();
    int n0 = wid*(CO/4);
    floatx4 acc[4][NF];
    #pragma unroll
    for (int mf = 0; mf < 4; mf++)
        #pragma unroll
        for (int nf = 0; nf < NF; nf++)
            #pragma unroll
            for (int r = 0; r < 4; r++) acc[mf][nf][r] = 0.f;
    for (int ks = 0; ks < KS; ks++) {
        int k = ks*32 + quad*8;
        half8_t a[4];
        #pragma unroll
        for (int mf = 0; mf < 4; mf++)
            a[mf] = *(const half8_t*)&a_lds[(mf*16 + l16)*LDR + k];
        half8_t bfr[NF];
        #pragma unroll
        for (int nf = 0; nf < NF; nf++) {
            int brow = n0 + l16*NF + nf;   // permuted rows: thread ends with NF consecutive co
            bfr[nf] = *(const half8_t*)&Wh[(size_t)brow*CI + k];
        }
        #pragma unroll
        for (int mf = 0; mf < 4; mf++)
            #pragma unroll
            for (int nf = 0; nf < NF; nf++)
                acc[mf][nf] = __builtin_amdgcn_mfma_f32_16x16x32_f16(a[mf], bfr[nf], acc[mf][nf], 0, 0, 0);
    }
    int cb = n0 + l16*NF;
    float bs[NF];
    #pragma unroll
    for (int j = 0; j < NF; j++) bs[j] = bias[cb + j];
    #pragma unroll
    for (int mf = 0; mf < 4; mf++) {
        #pragma unroll
        for (int r = 0; r < 4; r++) {
            int p = p0 + mf*16 + quad*4 + r;
            half4_t rh;
            if (RES == 2 && NF == 4) rh = *(const half4_t*)&res[(size_t)p*CO + cb];
            _Float16 tmp[NF];
            #pragma unroll
            for (int j = 0; j < NF; j++) {
                float v = acc[mf][j][r] + bs[j];
                if (ACT) v = gelu_f(v);
                if (RES == 2 && NF == 4) v += (float)rh[j];
                tmp[j] = (_Float16)v;
            }
            if (NF == 4) {
                half4_t o4; o4[0]=tmp[0]; o4[1]=tmp[1]; o4[2]=tmp[2]; o4[3]=tmp[3];
                *(half4_t*)&outh[(size_t)p*CO + cb] = o4;
            } else {
                half2_t o2; o2[0]=tmp[0]; o2[1]=tmp[1];
                *(half2_t*)&outh[(size_t)p*CO + cb] = o2;
            }
        }
    }
}

// ---------------- cv conv (256->256) fused with gate + LayerNorm over C ----------------
__global__ void __launch_bounds__(256) conv_cv_ln_kernel(const _Float16* __restrict__ in, const _Float16* __restrict__ Wh,
        const float* __restrict__ bias, const _Float16* __restrict__ X, const _Float16* __restrict__ IMG,
        const float* __restrict__ g, const float* __restrict__ bb2, _Float16* __restrict__ out) {
    constexpr int CI = 256, KS = 8, LDR = 264;
    __shared__ __align__(16) _Float16 a_lds[64*LDR];
    __shared__ float rs[64][4];
    __shared__ float rs2[64][4];
    __shared__ float st[64][2];
    int t = threadIdx.x;
    int wid = t >> 6, lane = t & 63;
    int quad = lane >> 4, l16 = lane & 15;
    int p0 = blockIdx.x * 64;
    {
        const half8_t* inh = (const half8_t*)in + (size_t)p0*32;
        for (int i = t; i < 2048; i += 256) {
            int r = i >> 5, c8 = i & 31;
            *(half8_t*)&a_lds[r*LDR + c8*8] = inh[i];
        }
    }
    __syncthreads();
    int n0 = wid*64;
    floatx4 acc[4][4];
    #pragma unroll
    for (int mf = 0; mf < 4; mf++)
        #pragma unroll
        for (int nf = 0; nf < 4; nf++)
            #pragma unroll
            for (int r = 0; r < 4; r++) acc[mf][nf][r] = 0.f;
    for (int ks = 0; ks < KS; ks++) {
        int k = ks*32 + quad*8;
        half8_t a[4];
        #pragma unroll
        for (int mf = 0; mf < 4; mf++)
            a[mf] = *(const half8_t*)&a_lds[(mf*16 + l16)*LDR + k];
        half8_t bfr[4];
        #pragma unroll
        for (int nf = 0; nf < 4; nf++)
            bfr[nf] = *(const half8_t*)&Wh[(size_t)(n0 + l16*4 + nf)*CI + k];
        #pragma unroll
        for (int mf = 0; mf < 4; mf++)
            #pragma unroll
            for (int nf = 0; nf < 4; nf++)
                acc[mf][nf] = __builtin_amdgcn_mfma_f32_16x16x32_f16(a[mf], bfr[nf], acc[mf][nf], 0, 0, 0);
    }
    int cb = n0 + l16*4;
    float bs[4];
    #pragma unroll
    for (int j = 0; j < 4; j++) bs[j] = bias[cb + j];
    #pragma unroll
    for (int mf = 0; mf < 4; mf++) {
        #pragma unroll
        for (int r = 0; r < 4; r++) {
            int px_l = mf*16 + quad*4 + r;
            size_t off = (size_t)(p0 + px_l)*256 + cb;
            half4_t xh = *(const half4_t*)&X[off];
            half4_t ih = *(const half4_t*)&IMG[off];
            float s = 0.f, s2 = 0.f;
            #pragma unroll
            for (int j = 0; j < 4; j++) {
                float v = acc[mf][j][r] + bs[j];
                v = (float)xh[j]*v + (float)ih[j];
                acc[mf][j][r] = v;
                s += v; s2 += v*v;
            }
            s += __shfl_xor(s, 1); s2 += __shfl_xor(s2, 1);
            s += __shfl_xor(s, 2); s2 += __shfl_xor(s2, 2);
            s += __shfl_xor(s, 4); s2 += __shfl_xor(s2, 4);
            s += __shfl_xor(s, 8); s2 += __shfl_xor(s2, 8);
            if (l16 == 0) { rs[px_l][wid] = s; rs2[px_l][wid] = s2; }
        }
    }
    __syncthreads();
    if (t < 64) {
        float m = 0.f, q = 0.f;
        #pragma unroll
        for (int w = 0; w < 4; w++) { m += rs[t][w]; q += rs2[t][w]; }
        m *= (1.0f/256.0f);
        float var = q*(1.0f/256.0f) - m*m;
        st[t][0] = m;
        st[t][1] = rsqrtf(var + 1e-5f);
    }
    __syncthreads();
    float ga[4], ba[4];
    #pragma unroll
    for (int j = 0; j < 4; j++) { ga[j] = g[cb + j]; ba[j] = bb2[cb + j]; }
    #pragma unroll
    for (int mf = 0; mf < 4; mf++) {
        #pragma unroll
        for (int r = 0; r < 4; r++) {
            int px_l = mf*16 + quad*4 + r;
            float m = st[px_l][0];
            float ri = st[px_l][1];
            half4_t o4;
            #pragma unroll
            for (int j = 0; j < 4; j++)
                o4[j] = (_Float16)((acc[mf][j][r] - m)*ri*ga[j] + ba[j]);
            *(half4_t*)&out[(size_t)(p0 + px_l)*256 + cb] = o4;
        }
    }
}

// ---------------- MFMA 3x3 offset conv (f16 input) -> [p][27] ----------------
template<int DIL>
__global__ void __launch_bounds__(256) off_conv_mfma(const _Float16* __restrict__ x, const _Float16* __restrict__ Wh,
        const float* __restrict__ bias, float* __restrict__ off) {
    constexpr int LDR = 264;    // 256 + 16B pad, halves
    __shared__ __align__(16) _Float16 xs[70*LDR];   // w = -3..66 at idx w+3
    int raw = blockIdx.x;
    int bh = (raw & 7) * 128 + (raw >> 3);
    int b = bh >> 6, h = bh & 63;
    int t = threadIdx.x;
    int wid = t >> 6, lane = t & 63;
    int quad = lane >> 4, l16 = lane & 15;
    for (int i = t; i < 6*LDR; i += 256) {
        int r = i/LDR, c = i%LDR;
        int row = (r < 3) ? r : (64 + r);   // 0,1,2, 67,68,69
        xs[row*LDR + c] = (_Float16)0.f;
    }
    floatx4 acc[2];
    #pragma unroll
    for (int nf = 0; nf < 2; nf++)
        #pragma unroll
        for (int r = 0; r < 4; r++) acc[nf][r] = 0.f;
    for (int ki = 0; ki < 3; ki++) {
        int hrow = h + (ki - 1)*DIL;
        __syncthreads();
        if (hrow >= 0 && hrow < 64) {
            const half8_t* row = (const half8_t*)(x + ((size_t)(b*64 + hrow)*64) * 256);
            for (int i = t; i < 2048; i += 256) {
                int r = i >> 5, c8 = i & 31;
                *(half8_t*)&xs[(r + 3)*LDR + c8*8] = row[r*32 + c8];
            }
        } else {
            half8_t z = (half8_t)((_Float16)0.f);
            for (int i = t; i < 2048; i += 256) {
                int r = i >> 5, c8 = i & 31;
                *(half8_t*)&xs[(r + 3)*LDR + c8*8] = z;
            }
        }
        __syncthreads();
        #pragma unroll
        for (int kj = 0; kj < 3; kj++) {
            const _Float16* wt = Wh + (size_t)(ki*3 + kj)*32*256;
            int wrow = wid*16 + l16 + (kj - 1)*DIL + 3;
            #pragma unroll
            for (int cs = 0; cs < 8; cs++) {
                int k = cs*32 + quad*8;
                half8_t a = *(const half8_t*)&xs[wrow*LDR + k];
                half8_t b0 = *(const half8_t*)&wt[(size_t)l16*256 + k];
                half8_t b1 = *(const half8_t*)&wt[(size_t)(16 + l16)*256 + k];
                acc[0] = __builtin_amdgcn_mfma_f32_16x16x32_f16(a, b0, acc[0], 0, 0, 0);
                acc[1] = __builtin_amdgcn_mfma_f32_16x16x32_f16(a, b1, acc[1], 0, 0, 0);
            }
        }
    }
    int pbase = (b*64 + h)*64;
    #pragma unroll
    for (int nf = 0; nf < 2; nf++) {
        int kcol = nf*16 + l16;
        if (kcol < 27) {
            float bs = bias[kcol];
            #pragma unroll
            for (int r = 0; r < 4; r++) {
                int w = wid*16 + quad*4 + r;
                off[(size_t)(pbase + w)*27 + kcol] = acc[nf][r] + bs;
            }
        }
    }
}

// ---------------- modulated deformable depthwise 3x3 (f16 src/out, fp32 math) ----------------
// grid = BB*HH*4 (w-quarters): finer blocks smooth the straggler tail.
// stage A: per-(w,tap) uniform bilinear weights + byte offsets in LDS.
// Inner: issue all 36 corner loads, sched_barrier(0) pin, then accumulate.
template<int DIL>
__global__ void __launch_bounds__(256) deform_kernel(const _Float16* __restrict__ src, const float* __restrict__ off,
        const float* __restrict__ dwt, const float* __restrict__ dwb, _Float16* __restrict__ out) {
    int raw = blockIdx.x;                       // 0..4095
    int swz = (raw & 7) * 512 + (raw >> 3);     // XCD k -> 2 consecutive batches
    int wq = swz & 3;
    int bh = swz >> 2;
    int b = bh >> 6, h = bh & 63;
    int t = threadIdx.x;
    int c4 = t & 63;
    int ps = t >> 6;

    __shared__ float4 wq4[144];
    __shared__ int4   iq4[144];
    __shared__ float  dw_lds[9*256];

    for (int i = t; i < 9*256; i += 256) dw_lds[i] = dwt[i];

    // stage A: 16 w x 9 taps, computed once per block
    for (int j = t; j < 144; j += 256) {
        int lw = j / 9;
        int kk = j - lw*9;
        int w = wq*16 + lw;
        int p = (b*64 + h)*64 + w;
        const float* op = off + (size_t)p*27;
        float ox = op[kk];
        float oy = op[9 + kk];
        float mm = op[18 + kk];
        mm = 1.0f / (1.0f + expf(-mm));
        int ki = kk / 3, kj = kk - ki*3;
        float py = (float)(h - DIL + ki*DIL) + oy;
        float px = (float)(w - DIL + kj*DIL) + ox;
        float y0f = floorf(py), x0f = floorf(px);
        float wy = py - y0f, wx = px - x0f;
        int y0 = (int)y0f, x0 = (int)x0f;
        int y1 = y0 + 1, x1 = x0 + 1;
        float w00 = (1.f - wy)*(1.f - wx)*mm;
        float w01 = (1.f - wy)*wx*mm;
        float w10 = wy*(1.f - wx)*mm;
        float w11 = wy*wx*mm;
        bool yv0 = (y0 >= 0) && (y0 < 64);
        bool yv1 = (y1 >= 0) && (y1 < 64);
        bool xv0 = (x0 >= 0) && (x0 < 64);
        bool xv1 = (x1 >= 0) && (x1 < 64);
        int y0c = min(max(y0, 0), 63), y1c = min(max(y1, 0), 63);
        int x0c = min(max(x0, 0), 63), x1c = min(max(x1, 0), 63);
        int base = b*4096;
        float4 wv;
        wv.x = (yv0 && xv0) ? w00 : 0.f;
        wv.y = (yv0 && xv1) ? w01 : 0.f;
        wv.z = (yv1 && xv0) ? w10 : 0.f;
        wv.w = (yv1 && xv1) ? w11 : 0.f;
        wq4[j] = wv;
        int4 iv;
        iv.x = (base + y0c*64 + x0c) << 9;   // *512 B per pixel (256 ch * 2B)
        iv.y = (base + y0c*64 + x1c) << 9;
        iv.z = (base + y1c*64 + x0c) << 9;
        iv.w = (base + y1c*64 + x1c) << 9;
        iq4[j] = iv;
    }
    __syncthreads();

    float4 bv = ((const float4*)dwb)[c4];
    const char* srcb = (const char*)src + (size_t)c4*8;
    for (int i = 0; i < 4; i++) {
        int lw = ps*4 + i;
        int jb = lw*9;
        int w = wq*16 + lw;
        int p = (b*64 + h)*64 + w;
        // phase A: issue all 36 corner loads (pinned below)
        half4_t v[9][4];
        #pragma unroll
        for (int kk = 0; kk < 9; kk++) {
            int4 iv = iq4[jb + kk];
            int o0 = __builtin_amdgcn_readfirstlane(iv.x);
            int o1 = __builtin_amdgcn_readfirstlane(iv.y);
            int o2 = __builtin_amdgcn_readfirstlane(iv.z);
            int o3 = __builtin_amdgcn_readfirstlane(iv.w);
            v[kk][0] = *(const half4_t*)(srcb + o0);
            v[kk][1] = *(const half4_t*)(srcb + o1);
            v[kk][2] = *(const half4_t*)(srcb + o2);
            v[kk][3] = *(const half4_t*)(srcb + o3);
        }
        __builtin_amdgcn_sched_barrier(0);   // do NOT sink loads past this point
        // phase B: accumulate
        float4 acc = make_float4(0.f,0.f,0.f,0.f);
        #pragma unroll
        for (int kk = 0; kk < 9; kk++) {
            float4 wv = wq4[jb + kk];
            float4 dw = ((const float4*)dw_lds)[kk*64 + c4];
            float sx = (float)v[kk][0][0]*wv.x + (float)v[kk][1][0]*wv.y + (float)v[kk][2][0]*wv.z + (float)v[kk][3][0]*wv.w;
            float sy = (float)v[kk][0][1]*wv.x + (float)v[kk][1][1]*wv.y + (float)v[kk][2][1]*wv.z + (float)v[kk][3][1]*wv.w;
            float sz = (float)v[kk][0][2]*wv.x + (float)v[kk][1][2]*wv.y + (float)v[kk][2][2]*wv.z + (float)v[kk][3][2]*wv.w;
            float sw = (float)v[kk][0][3]*wv.x + (float)v[kk][1][3]*wv.y + (float)v[kk][2][3]*wv.z + (float)v[kk][3][3]*wv.w;
            acc.x += sx * dw.x;
            acc.y += sy * dw.y;
            acc.z += sz * dw.z;
            acc.w += sw * dw.w;
        }
        half4_t o4;
        o4[0] = (_Float16)(acc.x + bv.x);
        o4[1] = (_Float16)(acc.y + bv.y);
        o4[2] = (_Float16)(acc.z + bv.z);
        o4[3] = (_Float16)(acc.w + bv.w);
        ((half4_t*)out)[(size_t)p*64 + c4] = o4;
    }
}

// ---------------- depthwise 3x3 pad=1 + gelu (NHWC, f16 in/out) ----------------
__global__ void __launch_bounds__(256) dw3x3_kernel(const _Float16* __restrict__ in, const float* __restrict__ wt,
        const float* __restrict__ bias, _Float16* __restrict__ out) {
    int raw = blockIdx.x;
    int swz = (raw & 7) * 2048 + (raw >> 3);
    int gid = swz*256 + threadIdx.x;
    int c4 = gid & 63;
    int p = gid >> 6;
    int w = p & 63;
    int h = (p >> 6) & 63;
    int b = p >> 12;
    float4 acc = ((const float4*)bias)[c4];
    #pragma unroll
    for (int ki = 0; ki < 3; ki++) {
        int hh = h + ki - 1;
        if (hh < 0 || hh >= 64) continue;
        #pragma unroll
        for (int kj = 0; kj < 3; kj++) {
            int wwp = w + kj - 1;
            if (wwp < 0 || wwp >= 64) continue;
            half4_t v = ((const half4_t*)in)[((b*64 + hh)*64 + wwp)*64 + c4];
            float4 wv = ((const float4*)wt)[(ki*3 + kj)*64 + c4];
            acc.x += (float)v[0]*wv.x; acc.y += (float)v[1]*wv.y;
            acc.z += (float)v[2]*wv.z; acc.w += (float)v[3]*wv.w;
        }
    }
    half4_t o4;
    o4[0] = (_Float16)gelu_f(acc.x);
    o4[1] = (_Float16)gelu_f(acc.y);
    o4[2] = (_Float16)gelu_f(acc.z);
    o4[3] = (_Float16)gelu_f(acc.w);
    ((half4_t*)out)[p*64 + c4] = o4;
}

// ---------------- fused: attn (MFMA) + out0 conv + out1 conv -> NCHW ----------------
// Per 64-px block, fully in LDS: scores = MFMA(d, t); softmax; att = PV + d*alpha
// (written in place over d); o0 = gelu(W0 x att); out = W1 x o0 -> NCHW fp32.
__global__ void __launch_bounds__(256) attn_out_fused(const _Float16* __restrict__ dense,
        const float* __restrict__ tok, const float* __restrict__ alpha,
        const _Float16* __restrict__ W0, const float* __restrict__ b0,
        const _Float16* __restrict__ W1, const float* __restrict__ b1,
        float* __restrict__ out) {
    __shared__ __align__(16) _Float16 d_att[64*264];     // dense tile, later att tile
    __shared__ __align__(16) _Float16 t_q[16*264];       // [q][c], rows 8..15 zero
    __shared__ __align__(16) _Float16 t_t[256*32];       // [c][q] stride 32 (64B rows, aligned), q>=8 zero
    __shared__ __align__(16) _Float16 w_lds[64*40];      // [px][k], k>=8 zero
    __shared__ __align__(16) _Float16 o0_lds[64*136];    // [px][c0]
    __shared__ float al_s[256];
    int t = threadIdx.x;
    int wid = t >> 6, lane = t & 63;
    int quad = lane >> 4, l16 = lane & 15;
    int p0 = blockIdx.x * 64;
    int b = p0 >> 12;

    for (int i = t; i < 16*264; i += 256) t_q[i] = (_Float16)0.f;
    for (int i = t; i < 256*32; i += 256) t_t[i] = (_Float16)0.f;
    for (int i = t; i < 64*40;  i += 256) w_lds[i] = (_Float16)0.f;
    __syncthreads();

    const half8_t* dh = (const half8_t*)dense + (size_t)p0*32;
    for (int i = t; i < 2048; i += 256) {
        int r = i >> 5, c8 = i & 31;
        *(half8_t*)&d_att[r*264 + c8*8] = dh[i];
    }
    for (int i = t; i < 512; i += 256) {
        int q = i >> 6, j = i & 63;
        float4 tv = ((const float4*)tok)[(b*8 + q)*64 + j];
        int c0 = j*4;
        t_q[q*264 + c0 + 0] = (_Float16)tv.x;
        t_q[q*264 + c0 + 1] = (_Float16)tv.y;
        t_q[q*264 + c0 + 2] = (_Float16)tv.z;
        t_q[q*264 + c0 + 3] = (_Float16)tv.w;
        t_t[(c0 + 0)*32 + q] = (_Float16)tv.x;
        t_t[(c0 + 1)*32 + q] = (_Float16)tv.y;
        t_t[(c0 + 2)*32 + q] = (_Float16)tv.z;
        t_t[(c0 + 3)*32 + q] = (_Float16)tv.w;
    }
    al_s[t] = alpha[t];
    __syncthreads();

    // GEMM1: scores[px][q]
    floatx4 s4;
    s4[0]=0.f; s4[1]=0.f; s4[2]=0.f; s4[3]=0.f;
    #pragma unroll
    for (int ks = 0; ks < 8; ks++) {
        int k = ks*32 + quad*8;
        half8_t a = *(const half8_t*)&d_att[(wid*16 + l16)*264 + k];
        half8_t bf = *(const half8_t*)&t_q[l16*264 + k];
        s4 = __builtin_amdgcn_mfma_f32_16x16x32_f16(a, bf, s4, 0, 0, 0);
    }
    // softmax over q (8-lane groups; lanes l16>=8 compute harmless zeros)
    float wgt[4];
    #pragma unroll
    for (int r = 0; r < 4; r++) {
        float sc = s4[r] * 0.0625f;
        float mx = sc;
        mx = fmaxf(mx, __shfl_xor(mx, 1));
        mx = fmaxf(mx, __shfl_xor(mx, 2));
        mx = fmaxf(mx, __shfl_xor(mx, 4));
        float e = expf(sc - mx);
        float dn = e;
        dn += __shfl_xor(dn, 1);
        dn += __shfl_xor(dn, 2);
        dn += __shfl_xor(dn, 4);
        wgt[r] = e / dn;
    }
    if (l16 < 8) {
        #pragma unroll
        for (int r = 0; r < 4; r++)
            w_lds[(wid*16 + quad*4 + r)*40 + l16] = (_Float16)wgt[r];
    }
    __syncthreads();

    // GEMM2 (perm-B: lane holds 16 consecutive co = l16*16..+15) + alpha residual,
    // written in place over d_att (each lane RMWs only its own (px, co) range).
    half8_t aw = *(const half8_t*)&w_lds[(wid*16 + l16)*40 + quad*8];
    floatx4 z4; z4[0]=0.f; z4[1]=0.f; z4[2]=0.f; z4[3]=0.f;
    floatx4 acc2[16];
    #pragma unroll
    for (int nf = 0; nf < 16; nf++) {
        half8_t bf = *(const half8_t*)&t_t[(l16*16 + nf)*32 + quad*8];
        acc2[nf] = __builtin_amdgcn_mfma_f32_16x16x32_f16(aw, bf, z4, 0, 0, 0);
    }
    int cb = l16*16;
    float alv[16];
    #pragma unroll
    for (int nf = 0; nf < 16; nf++) alv[nf] = al_s[cb + nf];
    #pragma unroll
    for (int r = 0; r < 4; r++) {
        int px = wid*16 + quad*4 + r;
        half8_t dlo = *(const half8_t*)&d_att[px*264 + cb];
        half8_t dhi = *(const half8_t*)&d_att[px*264 + cb + 8];
        half8_t olo, ohi;
        #pragma unroll
        for (int nf = 0; nf < 8; nf++) {
            olo[nf] = (_Float16)(acc2[nf][r]     + (float)dlo[nf]*alv[nf]);
            ohi[nf] = (_Float16)(acc2[nf + 8][r] + (float)dhi[nf]*alv[nf + 8]);
        }
        *(half8_t*)&d_att[px*264 + cb] = olo;
        *(half8_t*)&d_att[px*264 + cb + 8] = ohi;
    }
    __syncthreads();

    // out0: o0 = gelu(W0 x att), M=64 N=128 K=256, perm-B packed LDS stores
    int n0 = wid*32;
    floatx4 acc0[4][2];
    #pragma unroll
    for (int mf = 0; mf < 4; mf++)
        #pragma unroll
        for (int nf = 0; nf < 2; nf++)
            #pragma unroll
            for (int r = 0; r < 4; r++) acc0[mf][nf][r] = 0.f;
    #pragma unroll
    for (int ks = 0; ks < 8; ks++) {
        int k = ks*32 + quad*8;
        half8_t a[4];
        #pragma unroll
        for (int mf = 0; mf < 4; mf++)
            a[mf] = *(const half8_t*)&d_att[(mf*16 + l16)*264 + k];
        half8_t bf[2];
        #pragma unroll
        for (int nf = 0; nf < 2; nf++)
            bf[nf] = *(const half8_t*)&W0[(size_t)(n0 + l16*2 + nf)*256 + k];
        #pragma unroll
        for (int mf = 0; mf < 4; mf++)
            #pragma unroll
            for (int nf = 0; nf < 2; nf++)
                acc0[mf][nf] = __builtin_amdgcn_mfma_f32_16x16x32_f16(a[mf], bf[nf], acc0[mf][nf], 0, 0, 0);
    }
    int cb0 = n0 + l16*2;
    float bs0[2] = { b0[cb0], b0[cb0 + 1] };
    #pragma unroll
    for (int mf = 0; mf < 4; mf++) {
        #pragma unroll
        for (int r = 0; r < 4; r++) {
            int px = mf*16 + quad*4 + r;
            half2_t o2;
            o2[0] = (_Float16)gelu_f(acc0[mf][0][r] + bs0[0]);
            o2[1] = (_Float16)gelu_f(acc0[mf][1][r] + bs0[1]);
            *(half2_t*)&o0_lds[px*136 + cb0] = o2;
        }
    }
    __syncthreads();

    // out1: out = W1 x o0, M=64 N=256 K=128, standard B map, NCHW fp32 stores
    int n1 = wid*64;
    floatx4 acc1[4][4];
    #pragma unroll
    for (int mf = 0; mf < 4; mf++)
        #pragma unroll
        for (int nf = 0; nf < 4; nf++)
            #pragma unroll
            for (int r = 0; r < 4; r++) acc1[mf][nf][r] = 0.f;
    #pragma unroll
    for (int ks = 0; ks < 4; ks++) {
        int k = ks*32 + quad*8;
        half8_t a[4];
        #pragma unroll
        for (int mf = 0; mf < 4; mf++)
            a[mf] = *(const half8_t*)&o0_lds[(mf*16 + l16)*136 + k];
        half8_t bf[4];
        #pragma unroll
        for (int nf = 0; nf < 4; nf++)
            bf[nf] = *(const half8_t*)&W1[(size_t)(n1 + nf*16 + l16)*128 + k];
        #pragma unroll
        for (int mf = 0; mf < 4; mf++)
            #pragma unroll
            for (int nf = 0; nf < 4; nf++)
                acc1[mf][nf] = __builtin_amdgcn_mfma_f32_16x16x32_f16(a[mf], bf[nf], acc1[mf][nf], 0, 0, 0);
    }
    size_t bb = (size_t)b * ((size_t)CC * HWs) + (size_t)(p0 & 4095);
    #pragma unroll
    for (int nf = 0; nf < 4; nf++) {
        int co = n1 + nf*16 + l16;
        float bs = b1[co];
        #pragma unroll
        for (int mf = 0; mf < 4; mf++) {
            float4 vst;
            vst.x = acc1[mf][nf][0] + bs;
            vst.y = acc1[mf][nf][1] + bs;
            vst.z = acc1[mf][nf][2] + bs;
            vst.w = acc1[mf][nf][3] + bs;
            *(float4*)&out[bb + (size_t)co*HWs + mf*16 + quad*4] = vst;
        }
    }
}

extern "C" void kernel_launch(void* const* d_in, const int* in_sizes, int n_in,
                              void* d_out, int out_size, void* d_ws, size_t ws_size,
                              hipStream_t stream) {
    const float* image_embed = (const float*)d_in[0];
    const float* inter_p     = (const float*)d_in[1];
    const float* intra_p     = (const float*)d_in[2];
    const float* masks       = (const float*)d_in[3];
    const float* proj_w      = (const float*)d_in[4];
    const float* proj_b      = (const float*)d_in[5];
    const float* lin_w       = (const float*)d_in[6];
    const float* lin_b       = (const float*)d_in[7];
    const float* tok_g       = (const float*)d_in[8];
    const float* tok_b       = (const float*)d_in[9];
    const float* alpha       = (const float*)d_in[10];
    const float* in_w        = (const float*)d_in[11];
    const float* in_b        = (const float*)d_in[12];
    const float* off0_w      = (const float*)d_in[13];
    const float* off0_b      = (const float*)d_in[14];
    const float* dw0_w       = (const float*)d_in[15];
    const float* dw0_b       = (const float*)d_in[16];
    const float* off1_w      = (const float*)d_in[17];
    const float* off1_b      = (const float*)d_in[18];
    const float* dw1_w       = (const float*)d_in[19];
    const float* dw1_b       = (const float*)d_in[20];
    const float* cv_w        = (const float*)d_in[21];
    const float* cv_b        = (const float*)d_in[22];
    const float* ln_g        = (const float*)d_in[23];
    const float* ln_b        = (const float*)d_in[24];
    const float* op0_w       = (const float*)d_in[25];
    const float* op0_b       = (const float*)d_in[26];
    const float* op1_w       = (const float*)d_in[27];
    const float* op1_b       = (const float*)d_in[28];
    const float* op2_w       = (const float*)d_in[29];
    const float* op2_b       = (const float*)d_in[30];
    const float* out0_w      = (const float*)d_in[31];
    const float* out0_b      = (const float*)d_in[32];
    const float* out1_w      = (const float*)d_in[33];
    const float* out1_b      = (const float*)d_in[34];
    (void)ws_size; (void)in_sizes; (void)n_in; (void)out_size;

    float* ws = (float*)d_ws;
    const size_t BIG = (size_t)PP * CC;     // 16,777,216 floats (64 MiB)
    float* A   = ws;
    float* Bb  = A + BIG;
    float* Cb  = Bb + BIG;
    float* OFF = Cb + BIG;                  // [P][27]
    float* TOK = OFF + (size_t)PP*27;       // [16][8][256]
    float* DWT0 = TOK + BB*QQ*CC;
    float* DWT1 = DWT0 + 9*256;
    float* OP1T = DWT1 + 9*256;
    _Float16* WH_IN   = (_Float16*)(OP1T + 9*256);
    _Float16* WH_CV   = WH_IN + 65536;
    _Float16* WH_OP0  = WH_CV + 65536;
    _Float16* WH_OP2  = WH_OP0 + 65536;
    _Float16* WH_OUT0 = WH_OP2 + 65536;
    _Float16* WH_OUT1 = WH_OUT0 + 32768;
    _Float16* WHOFF0  = WH_OUT1 + 32768;
    _Float16* WHOFF1  = WHOFF0 + 9*32*256;
    // f16 tensor aliases (each 32 MiB = PP*CC halves)
    _Float16* IMGH = (_Float16*)A;               // img f16 (dead after cv_ln)
    _Float16* Y0H  = (_Float16*)A;               // op0 out (reuses IMGH)
    _Float16* Y1H  = Y0H + (size_t)PP*CC;        // dw3x3 out
    _Float16* XH   = (_Float16*)Bb;              // x f16 (dead after cv_ln)
    _Float16* A1H  = XH + (size_t)PP*CC;         // deform1 out
    _Float16* A2H  = (_Float16*)Cb;              // deform2 out (dead after cv_ln)
    _Float16* DENH = (_Float16*)Cb;              // dense (reuses A2H)
    _Float16* XLNH = (_Float16*)d_out;           // LN out (d_out; dead before final write)

    prep_weights_kernel<<<(9*32*256 + 255)/256, 256, 0, stream>>>(
        off0_w, off1_w, dw0_w, dw1_w, op1_w,
        in_w, cv_w, op0_w, op2_w, out0_w, out1_w,
        DWT0, DWT1, OP1T,
        WH_IN, WH_CV, WH_OP0, WH_OP2, WH_OUT0, WH_OUT1, WHOFF0, WHOFF1);
    token_kernel<<<BB*QQ, 256, 0, stream>>>(inter_p, intra_p, proj_w, proj_b,
                                            lin_w, lin_b, tok_g, tok_b, TOK);
    // img = ie*(1+pe) -> NHWC f16
    img_pe_kernel<<<dim3(HWs/32, CC/32, BB), dim3(32,8), 0, stream>>>(image_embed, intra_p, masks, IMGH);
    // x = gelu(conv1x1(img)) -> f16 (perm stores)
    conv1x1_mfma<256,256,1,0,1><<<PP/64, 256, 0, stream>>>(IMGH, WH_IN, in_b, nullptr, nullptr, XH);
    // deform block 1 (dil=1)
    off_conv_mfma<1><<<BB*HH, 256, 0, stream>>>(XH, WHOFF0, off0_b, OFF);
    deform_kernel<1><<<BB*HH*4, 256, 0, stream>>>(XH, OFF, DWT0, dw0_b, A1H);
    // deform block 2 (dil=3)
    off_conv_mfma<3><<<BB*HH, 256, 0, stream>>>(A1H, WHOFF1, off1_b, OFF);
    deform_kernel<3><<<BB*HH*4, 256, 0, stream>>>(A1H, OFF, DWT1, dw1_b, A2H);
    // x_ln = LN2d(x*conv(a2) + img) -> f16 (fused cv conv + gate + LN)
    conv_cv_ln_kernel<<<PP/64, 256, 0, stream>>>(A2H, WH_CV, cv_b, XH, IMGH, ln_g, ln_b, XLNH);
    // y0 = conv1x1(x_ln) -> f16
    conv1x1_mfma<256,256,0,0,1><<<PP/64, 256, 0, stream>>>(XLNH, WH_OP0, op0_b, nullptr, nullptr, Y0H);
    // y1 = gelu(dw3x3(y0)) -> f16
    dw3x3_kernel<<<PP*64/256, 256, 0, stream>>>(Y0H, OP1T, op1_b, Y1H);
    // dense = conv1x1(y1) + x_ln -> f16
    conv1x1_mfma<256,256,0,2,1><<<PP/64, 256, 0, stream>>>(Y1H, WH_OP2, op2_b, XLNH, nullptr, DENH);
    // fused: attn + out0 + out1 -> NCHW fp32 into d_out
    attn_out_fused<<<PP/64, 256, 0, stream>>>(DENH, TOK, alpha,
                                              WH_OUT0, out0_b, WH_OUT1, out1_b, (float*)d_out);
}